// Round 1
// baseline (11427.902 us; speedup 1.0000x reference)
//
#include <hip/hip_runtime.h>
#include <math.h>

#define N_NODES 65536
#define N_EDGES 524288
#define IN_CH 128
#define FHC 256
#define NCLS 3
#define NPG 32
#define NGRAPH (N_NODES / NPG)

#define BM 64
#define BN 64
#define BK 16
#define LDT 68  // padded LDS stride (floats): 16B-aligned float4 rows, <=2-way bank conflicts

__device__ inline float sigmoidf_(float x) { return 1.0f / (1.0f + expf(-x)); }

// ---------------- pad x [N,128] -> h [N,256] ----------------
__global__ void pad_kernel(const float* __restrict__ x, float* __restrict__ h) {
    int idx = blockIdx.x * blockDim.x + threadIdx.x;  // float4 granularity over N*64
    int c4 = idx & 63;
    int n = idx >> 6;
    float4 v = make_float4(0.f, 0.f, 0.f, 0.f);
    if (c4 < 32) v = reinterpret_cast<const float4*>(x)[n * 32 + c4];
    reinterpret_cast<float4*>(h)[idx] = v;
}

// ---------------- C[M,N] = A[M,K] @ B[K,N], row-major, fp32 ----------------
__global__ __launch_bounds__(256) void gemm_kernel(const float* __restrict__ A,
                                                   const float* __restrict__ B,
                                                   float* __restrict__ C,
                                                   int K, int N) {
    __shared__ __align__(16) float As[BK][LDT];  // transposed A tile [k][m]
    __shared__ __align__(16) float Bs[BK][LDT];  // B tile [k][n]
    int tid = threadIdx.x;
    int tx = tid & 15, ty = tid >> 4;
    int m0 = blockIdx.x * BM, n0 = blockIdx.y * BN;
    float acc[4][4] = {};
    for (int k0 = 0; k0 < K; k0 += BK) {
        int row = tid >> 2, kk = (tid & 3) << 2;
        float4 av = *reinterpret_cast<const float4*>(&A[(size_t)(m0 + row) * K + k0 + kk]);
        As[kk + 0][row] = av.x;
        As[kk + 1][row] = av.y;
        As[kk + 2][row] = av.z;
        As[kk + 3][row] = av.w;
        int kk2 = tid >> 4, jj = (tid & 15) << 2;
        *reinterpret_cast<float4*>(&Bs[kk2][jj]) =
            *reinterpret_cast<const float4*>(&B[(size_t)(k0 + kk2) * N + n0 + jj]);
        __syncthreads();
#pragma unroll
        for (int k = 0; k < BK; ++k) {
            float4 a4 = *reinterpret_cast<const float4*>(&As[k][ty * 4]);
            float4 b4 = *reinterpret_cast<const float4*>(&Bs[k][tx * 4]);
            float a[4] = {a4.x, a4.y, a4.z, a4.w};
            float b[4] = {b4.x, b4.y, b4.z, b4.w};
#pragma unroll
            for (int i = 0; i < 4; ++i)
#pragma unroll
                for (int j = 0; j < 4; ++j) acc[i][j] += a[i] * b[j];
        }
        __syncthreads();
    }
#pragma unroll
    for (int i = 0; i < 4; ++i) {
        float4 v = make_float4(acc[i][0], acc[i][1], acc[i][2], acc[i][3]);
        *reinterpret_cast<float4*>(&C[(size_t)(m0 + ty * 4 + i) * N + n0 + tx * 4]) = v;
    }
}

// ---------------- scatter: agg[dst] += m[src] * ea ----------------
__global__ void scatter_kernel(const float* __restrict__ m, const int* __restrict__ ei,
                               const float* __restrict__ ea, float* __restrict__ agg) {
    int e = blockIdx.x * 4 + (threadIdx.x >> 6);
    int lane = threadIdx.x & 63;
    int src = ei[e];
    int dst = ei[N_EDGES + e];
    float w = ea[e];
    float4 v = reinterpret_cast<const float4*>(m)[(size_t)src * 64 + lane];
    float* o = &agg[(size_t)dst * FHC + lane * 4];
    atomicAdd(o + 0, v.x * w);
    atomicAdd(o + 1, v.y * w);
    atomicAdd(o + 2, v.z * w);
    atomicAdd(o + 3, v.w * w);
}

// ---------------- fused GRU: hout = GRU(agg, h) ----------------
// accR = agg.w_ih[c] + h.w_hh[c]; accZ same at c+256; accG = agg.w_ih[c+512]; accH = h.w_hh[c+512]
__global__ __launch_bounds__(256) void gru_kernel(
    const float* __restrict__ agg, const float* __restrict__ h,
    const float* __restrict__ wih, const float* __restrict__ whh,
    const float* __restrict__ bih, const float* __restrict__ bhh,
    float* __restrict__ hout) {
    __shared__ __align__(16) float As[BK][LDT];
    __shared__ __align__(16) float Hs[BK][LDT];
    __shared__ __align__(16) float Wir[BK][LDT], Wiz[BK][LDT], Wig[BK][LDT];
    __shared__ __align__(16) float Whr[BK][LDT], Whz[BK][LDT], Whg[BK][LDT];
    int tid = threadIdx.x;
    int tx = tid & 15, ty = tid >> 4;
    int m0 = blockIdx.x * BM;
    int c0 = blockIdx.y * BN;
    float accR[4][4] = {}, accZ[4][4] = {}, accG[4][4] = {}, accH[4][4] = {};
    for (int k0 = 0; k0 < FHC; k0 += BK) {
        int row = tid >> 2, kk = (tid & 3) << 2;
        float4 av = *reinterpret_cast<const float4*>(&agg[(size_t)(m0 + row) * FHC + k0 + kk]);
        float4 hv = *reinterpret_cast<const float4*>(&h[(size_t)(m0 + row) * FHC + k0 + kk]);
        float4 w0 = *reinterpret_cast<const float4*>(&wih[(size_t)(c0 + row) * FHC + k0 + kk]);
        float4 w1 = *reinterpret_cast<const float4*>(&wih[(size_t)(c0 + 256 + row) * FHC + k0 + kk]);
        float4 w2 = *reinterpret_cast<const float4*>(&wih[(size_t)(c0 + 512 + row) * FHC + k0 + kk]);
        float4 w3 = *reinterpret_cast<const float4*>(&whh[(size_t)(c0 + row) * FHC + k0 + kk]);
        float4 w4 = *reinterpret_cast<const float4*>(&whh[(size_t)(c0 + 256 + row) * FHC + k0 + kk]);
        float4 w5 = *reinterpret_cast<const float4*>(&whh[(size_t)(c0 + 512 + row) * FHC + k0 + kk]);
        As[kk + 0][row] = av.x; As[kk + 1][row] = av.y; As[kk + 2][row] = av.z; As[kk + 3][row] = av.w;
        Hs[kk + 0][row] = hv.x; Hs[kk + 1][row] = hv.y; Hs[kk + 2][row] = hv.z; Hs[kk + 3][row] = hv.w;
        Wir[kk + 0][row] = w0.x; Wir[kk + 1][row] = w0.y; Wir[kk + 2][row] = w0.z; Wir[kk + 3][row] = w0.w;
        Wiz[kk + 0][row] = w1.x; Wiz[kk + 1][row] = w1.y; Wiz[kk + 2][row] = w1.z; Wiz[kk + 3][row] = w1.w;
        Wig[kk + 0][row] = w2.x; Wig[kk + 1][row] = w2.y; Wig[kk + 2][row] = w2.z; Wig[kk + 3][row] = w2.w;
        Whr[kk + 0][row] = w3.x; Whr[kk + 1][row] = w3.y; Whr[kk + 2][row] = w3.z; Whr[kk + 3][row] = w3.w;
        Whz[kk + 0][row] = w4.x; Whz[kk + 1][row] = w4.y; Whz[kk + 2][row] = w4.z; Whz[kk + 3][row] = w4.w;
        Whg[kk + 0][row] = w5.x; Whg[kk + 1][row] = w5.y; Whg[kk + 2][row] = w5.z; Whg[kk + 3][row] = w5.w;
        __syncthreads();
#pragma unroll
        for (int k = 0; k < BK; ++k) {
            float4 a4 = *reinterpret_cast<const float4*>(&As[k][ty * 4]);
            float4 h4 = *reinterpret_cast<const float4*>(&Hs[k][ty * 4]);
            float4 r4 = *reinterpret_cast<const float4*>(&Wir[k][tx * 4]);
            float4 z4 = *reinterpret_cast<const float4*>(&Wiz[k][tx * 4]);
            float4 g4 = *reinterpret_cast<const float4*>(&Wig[k][tx * 4]);
            float4 R4 = *reinterpret_cast<const float4*>(&Whr[k][tx * 4]);
            float4 Z4 = *reinterpret_cast<const float4*>(&Whz[k][tx * 4]);
            float4 G4 = *reinterpret_cast<const float4*>(&Whg[k][tx * 4]);
            float a[4] = {a4.x, a4.y, a4.z, a4.w};
            float hh[4] = {h4.x, h4.y, h4.z, h4.w};
            float wr[4] = {r4.x, r4.y, r4.z, r4.w};
            float wz[4] = {z4.x, z4.y, z4.z, z4.w};
            float wg[4] = {g4.x, g4.y, g4.z, g4.w};
            float WR[4] = {R4.x, R4.y, R4.z, R4.w};
            float WZ[4] = {Z4.x, Z4.y, Z4.z, Z4.w};
            float WG[4] = {G4.x, G4.y, G4.z, G4.w};
#pragma unroll
            for (int i = 0; i < 4; ++i)
#pragma unroll
                for (int j = 0; j < 4; ++j) {
                    accR[i][j] += a[i] * wr[j] + hh[i] * WR[j];
                    accZ[i][j] += a[i] * wz[j] + hh[i] * WZ[j];
                    accG[i][j] += a[i] * wg[j];
                    accH[i][j] += hh[i] * WG[j];
                }
        }
        __syncthreads();
    }
#pragma unroll
    for (int i = 0; i < 4; ++i) {
        int node = m0 + ty * 4 + i;
        float4 hold = *reinterpret_cast<const float4*>(&h[(size_t)node * FHC + c0 + tx * 4]);
        float hvv[4] = {hold.x, hold.y, hold.z, hold.w};
        float ho[4];
#pragma unroll
        for (int j = 0; j < 4; ++j) {
            int c = c0 + tx * 4 + j;
            float r = sigmoidf_(accR[i][j] + bih[c] + bhh[c]);
            float z = sigmoidf_(accZ[i][j] + bih[c + 256] + bhh[c + 256]);
            float g = tanhf(accG[i][j] + bih[c + 512] + r * (accH[i][j] + bhh[c + 512]));
            ho[j] = (1.f - z) * g + z * hvv[j];
        }
        *reinterpret_cast<float4*>(&hout[(size_t)node * FHC + c0 + tx * 4]) =
            make_float4(ho[0], ho[1], ho[2], ho[3]);
    }
}

// ---------------- conv1d(k=1) head: y1[n] = relu(sum_f relu(h[n,f])*w[f] + b) ----------------
__global__ void cnn_kernel(const float* __restrict__ h, const float* __restrict__ w,
                           const float* __restrict__ b, float* __restrict__ y1) {
    int node = blockIdx.x * 4 + (threadIdx.x >> 6);
    int lane = threadIdx.x & 63;
    float4 hv = reinterpret_cast<const float4*>(h)[(size_t)node * 64 + lane];
    float4 wv = reinterpret_cast<const float4*>(w)[lane];
    float p = fmaxf(hv.x, 0.f) * wv.x + fmaxf(hv.y, 0.f) * wv.y +
              fmaxf(hv.z, 0.f) * wv.z + fmaxf(hv.w, 0.f) * wv.w;
#pragma unroll
    for (int off = 32; off > 0; off >>= 1) p += __shfl_down(p, off, 64);
    if (lane == 0) y1[node] = fmaxf(p + b[0], 0.f);
}

// ---------------- per-graph MLP + softmax ----------------
__global__ __launch_bounds__(256) void head_kernel(
    const float* __restrict__ y1, const float* __restrict__ l1w,
    const float* __restrict__ l1b, const float* __restrict__ l2w,
    const float* __restrict__ l2b, float* __restrict__ out) {
    __shared__ float ys[32];
    __shared__ float zs[256];
    __shared__ float os[3];
    int b = blockIdx.x, tid = threadIdx.x;
    if (tid < 32) ys[tid] = y1[b * 32 + tid];
    __syncthreads();
    float acc = l1b[tid];
#pragma unroll
    for (int k = 0; k < 32; ++k) acc += ys[k] * l1w[tid * 32 + k];
    zs[tid] = fmaxf(acc, 0.f);
    __syncthreads();
    int wave = tid >> 6, lane = tid & 63;
    if (wave < 3) {
        float p = 0.f;
#pragma unroll
        for (int j = 0; j < 4; ++j) p += zs[lane + j * 64] * l2w[wave * 256 + lane + j * 64];
#pragma unroll
        for (int off = 32; off > 0; off >>= 1) p += __shfl_down(p, off, 64);
        if (lane == 0) os[wave] = p + l2b[wave];
    }
    __syncthreads();
    if (tid == 0) {
        float mx = fmaxf(os[0], fmaxf(os[1], os[2]));
        float e0 = expf(os[0] - mx), e1 = expf(os[1] - mx), e2 = expf(os[2] - mx);
        float s = e0 + e1 + e2;
        out[b * 3 + 0] = e0 / s;
        out[b * 3 + 1] = e1 / s;
        out[b * 3 + 2] = e2 / s;
    }
}

extern "C" void kernel_launch(void* const* d_in, const int* in_sizes, int n_in,
                              void* d_out, int out_size, void* d_ws, size_t ws_size,
                              hipStream_t stream) {
    const float* x = (const float*)d_in[0];
    const int* ei = (const int*)d_in[1];
    const float* ea = (const float*)d_in[2];
    const float* gg_w = (const float*)d_in[3];
    const float* w_ih = (const float*)d_in[4];
    const float* w_hh = (const float*)d_in[5];
    const float* b_ih = (const float*)d_in[6];
    const float* b_hh = (const float*)d_in[7];
    const float* cnn_w = (const float*)d_in[8];
    const float* cnn_b = (const float*)d_in[9];
    const float* l1w = (const float*)d_in[10];
    const float* l1b = (const float*)d_in[11];
    const float* l2w = (const float*)d_in[12];
    const float* l2b = (const float*)d_in[13];
    float* out = (float*)d_out;

    size_t bufElems = (size_t)N_NODES * FHC;
    float* buf0 = (float*)d_ws;          // h
    float* buf1 = buf0 + bufElems;       // m / h_new
    float* buf2 = buf1 + bufElems;       // agg
    float* y1 = buf2 + bufElems;         // [N_NODES]

    dim3 ggrid(N_NODES / BM, FHC / BN);

    pad_kernel<<<N_NODES * 64 / 256, 256, 0, stream>>>(x, buf0);

    // layer 0: h=buf0 -> m=buf1 -> agg=buf2 -> h1=buf1
    gemm_kernel<<<ggrid, 256, 0, stream>>>(buf0, gg_w, buf1, FHC, FHC);
    hipMemsetAsync(buf2, 0, bufElems * sizeof(float), stream);
    scatter_kernel<<<N_EDGES / 4, 256, 0, stream>>>(buf1, ei, ea, buf2);
    gru_kernel<<<ggrid, 256, 0, stream>>>(buf2, buf0, w_ih, w_hh, b_ih, b_hh, buf1);

    // layer 1: h=buf1 -> m=buf0 -> agg=buf2 -> h2=buf0
    gemm_kernel<<<ggrid, 256, 0, stream>>>(buf1, gg_w + FHC * FHC, buf0, FHC, FHC);
    hipMemsetAsync(buf2, 0, bufElems * sizeof(float), stream);
    scatter_kernel<<<N_EDGES / 4, 256, 0, stream>>>(buf0, ei, ea, buf2);
    gru_kernel<<<ggrid, 256, 0, stream>>>(buf2, buf1, w_ih, w_hh, b_ih, b_hh, buf0);

    cnn_kernel<<<N_NODES / 4, 256, 0, stream>>>(buf0, cnn_w, cnn_b, y1);
    head_kernel<<<NGRAPH, 256, 0, stream>>>(y1, l1w, l1b, l2w, l2b, out);
}

// Round 2
// 3870.974 us; speedup vs baseline: 2.9522x; 2.9522x over previous
//
#include <hip/hip_runtime.h>
#include <math.h>

#define N_NODES 65536
#define N_EDGES 524288
#define IN_CH 128
#define FHC 256
#define NCLS 3
#define NPG 32
#define NGRAPH (N_NODES / NPG)

#define LDW 40  // shorts per LDS tile row (32 data + 8 pad) = 80B stride -> bank-uniform b128 reads

typedef __attribute__((ext_vector_type(8))) short bfrag;   // 8 bf16 = 4 VGPR (MFMA A/B)
typedef __attribute__((ext_vector_type(4))) float facc;    // 4 f32 (MFMA C/D)

__device__ inline float sigmoidf_(float x) { return 1.0f / (1.0f + expf(-x)); }

__device__ inline short f2bf(float f) {  // RNE float->bf16 bits
    union { float f; unsigned u; } v; v.f = f;
    unsigned r = v.u + 0x7fffu + ((v.u >> 16) & 1u);
    return (short)(r >> 16);
}
__device__ inline float bf2f(short s) {
    union { unsigned u; float f; } v; v.u = ((unsigned)(unsigned short)s) << 16;
    return v.f;
}

// ---------------- weight convert: gg_w -> transposed bf16, w_ih/w_hh -> bf16 ----------------
__global__ void convert_kernel(const float* __restrict__ gg_w, const float* __restrict__ wih,
                               const float* __restrict__ whh, short* __restrict__ ggT,
                               short* __restrict__ wih16, short* __restrict__ whh16) {
    int t = blockIdx.x * 256 + threadIdx.x;  // 0 .. 524287
    if (t < 2 * FHC * FHC) {
        int i = t >> 16, r = t & 65535, n = r >> 8, k = r & 255;
        ggT[t] = f2bf(gg_w[i * FHC * FHC + k * FHC + n]);  // out [i][n][k]
    } else if (t < 2 * FHC * FHC + 3 * FHC * FHC) {
        int u = t - 2 * FHC * FHC;
        wih16[u] = f2bf(wih[u]);
    } else {
        int u = t - 5 * FHC * FHC;
        whh16[u] = f2bf(whh[u]);
    }
}

// ---------------- pad x [N,128] fp32 -> h [N,256] bf16 ----------------
__global__ void pad16_kernel(const float* __restrict__ x, short* __restrict__ h) {
    int idx = blockIdx.x * 256 + threadIdx.x;  // short4 granularity over N*64
    int c4 = idx & 63, n = idx >> 6;
    short4 v = {0, 0, 0, 0};
    if (c4 < 32) {
        float4 xv = reinterpret_cast<const float4*>(x)[n * 32 + c4];
        v.x = f2bf(xv.x); v.y = f2bf(xv.y); v.z = f2bf(xv.z); v.w = f2bf(xv.w);
    }
    reinterpret_cast<short4*>(h)[idx] = v;
}

// ---------------- m16[M,256] = h16[M,256] @ W[256(n),256(k)]^T  (bf16 MFMA) ----------------
__global__ __launch_bounds__(256) void mgemm_kernel(const short* __restrict__ A,
                                                    const short* __restrict__ W,
                                                    short* __restrict__ C) {
    __shared__ __align__(16) short As[64 * LDW];
    __shared__ __align__(16) short Ws[64 * LDW];
    int tid = threadIdx.x;
    int m0 = blockIdx.x * 64, n0 = blockIdx.y * 64;
    int srow = tid >> 2, sch = tid & 3;
    int lane = tid & 63, wv = tid >> 6, fr = lane & 15, fc = lane >> 4;
    facc acc[4] = {};
    for (int k0 = 0; k0 < FHC; k0 += 32) {
        *reinterpret_cast<int4*>(&As[srow * LDW + sch * 8]) =
            *reinterpret_cast<const int4*>(&A[(size_t)(m0 + srow) * FHC + k0 + sch * 8]);
        *reinterpret_cast<int4*>(&Ws[srow * LDW + sch * 8]) =
            *reinterpret_cast<const int4*>(&W[(size_t)(n0 + srow) * FHC + k0 + sch * 8]);
        __syncthreads();
        bfrag af = *reinterpret_cast<bfrag*>(&As[(wv * 16 + fr) * LDW + fc * 8]);
#pragma unroll
        for (int cf = 0; cf < 4; ++cf) {
            bfrag bf_ = *reinterpret_cast<bfrag*>(&Ws[(cf * 16 + fr) * LDW + fc * 8]);
            acc[cf] = __builtin_amdgcn_mfma_f32_16x16x32_bf16(af, bf_, acc[cf], 0, 0, 0);
        }
        __syncthreads();
    }
#pragma unroll
    for (int cf = 0; cf < 4; ++cf)
#pragma unroll
        for (int r = 0; r < 4; ++r) {
            int node = m0 + wv * 16 + fc * 4 + r;
            int c = n0 + cf * 16 + fr;
            C[(size_t)node * FHC + c] = f2bf(acc[cf][r]);
        }
}

// ---------------- scatter: agg[dst] += m16[src] * ea  (fp32 atomics) ----------------
__global__ void scatter_kernel(const short* __restrict__ m, const int* __restrict__ ei,
                               const float* __restrict__ ea, float* __restrict__ agg) {
    int e = blockIdx.x * 4 + (threadIdx.x >> 6);
    int lane = threadIdx.x & 63;
    int src = ei[e];
    int dst = ei[N_EDGES + e];
    float w = ea[e];
    short4 v = reinterpret_cast<const short4*>(m)[(size_t)src * 64 + lane];
    float* o = &agg[(size_t)dst * FHC + lane * 4];
    atomicAdd(o + 0, bf2f(v.x) * w);
    atomicAdd(o + 1, bf2f(v.y) * w);
    atomicAdd(o + 2, bf2f(v.z) * w);
    atomicAdd(o + 3, bf2f(v.w) * w);
}

// ---------------- fused GRU via MFMA: hout = GRU(agg, hin) ----------------
// aR = agg.wir^T + h.whr^T ; aZ likewise ; aG = agg.wig^T ; aH = h.whg^T
__global__ __launch_bounds__(256) void gru_mfma_kernel(
    const float* __restrict__ agg, const short* __restrict__ hin, short* __restrict__ hout,
    const short* __restrict__ wih16, const short* __restrict__ whh16,
    const float* __restrict__ bih, const float* __restrict__ bhh) {
    __shared__ __align__(16) short AggS[64 * LDW], HS[64 * LDW];
    __shared__ __align__(16) short WirS[64 * LDW], WizS[64 * LDW], WigS[64 * LDW];
    __shared__ __align__(16) short WhrS[64 * LDW], WhzS[64 * LDW], WhgS[64 * LDW];
    int tid = threadIdx.x;
    int m0 = blockIdx.x * 64, c0 = blockIdx.y * 64;
    int srow = tid >> 2, sch = tid & 3;
    int lane = tid & 63, wv = tid >> 6, fr = lane & 15, fc = lane >> 4;
    facc aR[4] = {}, aZ[4] = {}, aG[4] = {}, aH[4] = {};
    for (int k0 = 0; k0 < FHC; k0 += 32) {
        // stage agg (fp32 -> bf16)
        {
            const float* ap = &agg[(size_t)(m0 + srow) * FHC + k0 + sch * 8];
            float4 a0 = *reinterpret_cast<const float4*>(ap);
            float4 a1 = *reinterpret_cast<const float4*>(ap + 4);
            bfrag av;
            av[0] = f2bf(a0.x); av[1] = f2bf(a0.y); av[2] = f2bf(a0.z); av[3] = f2bf(a0.w);
            av[4] = f2bf(a1.x); av[5] = f2bf(a1.y); av[6] = f2bf(a1.z); av[7] = f2bf(a1.w);
            *reinterpret_cast<bfrag*>(&AggS[srow * LDW + sch * 8]) = av;
        }
        // stage h + 6 weight tiles (bf16 16B copies)
        size_t koff = (size_t)k0 + sch * 8;
        *reinterpret_cast<int4*>(&HS[srow * LDW + sch * 8]) =
            *reinterpret_cast<const int4*>(&hin[(size_t)(m0 + srow) * FHC + koff]);
        *reinterpret_cast<int4*>(&WirS[srow * LDW + sch * 8]) =
            *reinterpret_cast<const int4*>(&wih16[(size_t)(c0 + srow) * FHC + koff]);
        *reinterpret_cast<int4*>(&WizS[srow * LDW + sch * 8]) =
            *reinterpret_cast<const int4*>(&wih16[(size_t)(c0 + 256 + srow) * FHC + koff]);
        *reinterpret_cast<int4*>(&WigS[srow * LDW + sch * 8]) =
            *reinterpret_cast<const int4*>(&wih16[(size_t)(c0 + 512 + srow) * FHC + koff]);
        *reinterpret_cast<int4*>(&WhrS[srow * LDW + sch * 8]) =
            *reinterpret_cast<const int4*>(&whh16[(size_t)(c0 + srow) * FHC + koff]);
        *reinterpret_cast<int4*>(&WhzS[srow * LDW + sch * 8]) =
            *reinterpret_cast<const int4*>(&whh16[(size_t)(c0 + 256 + srow) * FHC + koff]);
        *reinterpret_cast<int4*>(&WhgS[srow * LDW + sch * 8]) =
            *reinterpret_cast<const int4*>(&whh16[(size_t)(c0 + 512 + srow) * FHC + koff]);
        __syncthreads();
        bfrag aggF = *reinterpret_cast<bfrag*>(&AggS[(wv * 16 + fr) * LDW + fc * 8]);
        bfrag hF = *reinterpret_cast<bfrag*>(&HS[(wv * 16 + fr) * LDW + fc * 8]);
#pragma unroll
        for (int cf = 0; cf < 4; ++cf) {
            int ro = (cf * 16 + fr) * LDW + fc * 8;
            bfrag wir = *reinterpret_cast<bfrag*>(&WirS[ro]);
            bfrag wiz = *reinterpret_cast<bfrag*>(&WizS[ro]);
            bfrag wig = *reinterpret_cast<bfrag*>(&WigS[ro]);
            bfrag whr = *reinterpret_cast<bfrag*>(&WhrS[ro]);
            bfrag whz = *reinterpret_cast<bfrag*>(&WhzS[ro]);
            bfrag whg = *reinterpret_cast<bfrag*>(&WhgS[ro]);
            aR[cf] = __builtin_amdgcn_mfma_f32_16x16x32_bf16(aggF, wir, aR[cf], 0, 0, 0);
            aR[cf] = __builtin_amdgcn_mfma_f32_16x16x32_bf16(hF, whr, aR[cf], 0, 0, 0);
            aZ[cf] = __builtin_amdgcn_mfma_f32_16x16x32_bf16(aggF, wiz, aZ[cf], 0, 0, 0);
            aZ[cf] = __builtin_amdgcn_mfma_f32_16x16x32_bf16(hF, whz, aZ[cf], 0, 0, 0);
            aG[cf] = __builtin_amdgcn_mfma_f32_16x16x32_bf16(aggF, wig, aG[cf], 0, 0, 0);
            aH[cf] = __builtin_amdgcn_mfma_f32_16x16x32_bf16(hF, whg, aH[cf], 0, 0, 0);
        }
        __syncthreads();
    }
#pragma unroll
    for (int cf = 0; cf < 4; ++cf) {
        int c = c0 + cf * 16 + fr;
        float br = bih[c] + bhh[c];
        float bz = bih[c + 256] + bhh[c + 256];
        float big = bih[c + 512];
        float bhg = bhh[c + 512];
#pragma unroll
        for (int r = 0; r < 4; ++r) {
            int node = m0 + wv * 16 + fc * 4 + r;
            float hold = bf2f(hin[(size_t)node * FHC + c]);
            float rg = sigmoidf_(aR[cf][r] + br);
            float z = sigmoidf_(aZ[cf][r] + bz);
            float g = tanhf(aG[cf][r] + big + rg * (aH[cf][r] + bhg));
            hout[(size_t)node * FHC + c] = f2bf((1.f - z) * g + z * hold);
        }
    }
}

// ---------------- conv1d(k=1) head: y1[n] = relu(sum_f relu(h[n,f])*w[f] + b) ----------------
__global__ void cnn_kernel(const short* __restrict__ h, const float* __restrict__ w,
                           const float* __restrict__ b, float* __restrict__ y1) {
    int node = blockIdx.x * 4 + (threadIdx.x >> 6);
    int lane = threadIdx.x & 63;
    short4 hv = reinterpret_cast<const short4*>(h)[(size_t)node * 64 + lane];
    float4 wv = reinterpret_cast<const float4*>(w)[lane];
    float p = fmaxf(bf2f(hv.x), 0.f) * wv.x + fmaxf(bf2f(hv.y), 0.f) * wv.y +
              fmaxf(bf2f(hv.z), 0.f) * wv.z + fmaxf(bf2f(hv.w), 0.f) * wv.w;
#pragma unroll
    for (int off = 32; off > 0; off >>= 1) p += __shfl_down(p, off, 64);
    if (lane == 0) y1[node] = fmaxf(p + b[0], 0.f);
}

// ---------------- per-graph MLP + softmax ----------------
__global__ __launch_bounds__(256) void head_kernel(
    const float* __restrict__ y1, const float* __restrict__ l1w,
    const float* __restrict__ l1b, const float* __restrict__ l2w,
    const float* __restrict__ l2b, float* __restrict__ out) {
    __shared__ float ys[32];
    __shared__ float zs[256];
    __shared__ float os[3];
    int b = blockIdx.x, tid = threadIdx.x;
    if (tid < 32) ys[tid] = y1[b * 32 + tid];
    __syncthreads();
    float acc = l1b[tid];
#pragma unroll
    for (int k = 0; k < 32; ++k) acc += ys[k] * l1w[tid * 32 + k];
    zs[tid] = fmaxf(acc, 0.f);
    __syncthreads();
    int wave = tid >> 6, lane = tid & 63;
    if (wave < 3) {
        float p = 0.f;
#pragma unroll
        for (int j = 0; j < 4; ++j) p += zs[lane + j * 64] * l2w[wave * 256 + lane + j * 64];
#pragma unroll
        for (int off = 32; off > 0; off >>= 1) p += __shfl_down(p, off, 64);
        if (lane == 0) os[wave] = p + l2b[wave];
    }
    __syncthreads();
    if (tid == 0) {
        float mx = fmaxf(os[0], fmaxf(os[1], os[2]));
        float e0 = expf(os[0] - mx), e1 = expf(os[1] - mx), e2 = expf(os[2] - mx);
        float s = e0 + e1 + e2;
        out[b * 3 + 0] = e0 / s;
        out[b * 3 + 1] = e1 / s;
        out[b * 3 + 2] = e2 / s;
    }
}

extern "C" void kernel_launch(void* const* d_in, const int* in_sizes, int n_in,
                              void* d_out, int out_size, void* d_ws, size_t ws_size,
                              hipStream_t stream) {
    const float* x = (const float*)d_in[0];
    const int* ei = (const int*)d_in[1];
    const float* ea = (const float*)d_in[2];
    const float* gg_w = (const float*)d_in[3];
    const float* w_ih = (const float*)d_in[4];
    const float* w_hh = (const float*)d_in[5];
    const float* b_ih = (const float*)d_in[6];
    const float* b_hh = (const float*)d_in[7];
    const float* cnn_w = (const float*)d_in[8];
    const float* cnn_b = (const float*)d_in[9];
    const float* l1w = (const float*)d_in[10];
    const float* l1b = (const float*)d_in[11];
    const float* l2w = (const float*)d_in[12];
    const float* l2b = (const float*)d_in[13];
    float* out = (float*)d_out;

    const size_t nodeE = (size_t)N_NODES * FHC;
    char* base = (char*)d_ws;
    short* hA = (short*)base;                         // 32 MB
    short* hB = (short*)(base + nodeE * 2);           // 32 MB
    short* m16 = (short*)(base + nodeE * 4);          // 32 MB
    float* agg = (float*)(base + nodeE * 6);          // 64 MB
    char* wbase = base + nodeE * 6 + nodeE * 4;
    short* ggT = (short*)wbase;                       // 2*256*256
    short* wih16 = ggT + 2 * FHC * FHC;               // 768*256
    short* whh16 = wih16 + 3 * FHC * FHC;             // 768*256
    float* y1 = (float*)(wbase + (2 + 3 + 3) * FHC * FHC * 2);

    dim3 ggrid(N_NODES / 64, FHC / 64);

    convert_kernel<<<8 * FHC * FHC / 256, 256, 0, stream>>>(gg_w, w_ih, w_hh, ggT, wih16, whh16);
    pad16_kernel<<<N_NODES * 64 / 256, 256, 0, stream>>>(x, hA);

    // layer 0: hA -> m16 -> agg -> hB
    mgemm_kernel<<<ggrid, 256, 0, stream>>>(hA, ggT, m16);
    hipMemsetAsync(agg, 0, nodeE * sizeof(float), stream);
    scatter_kernel<<<N_EDGES / 4, 256, 0, stream>>>(m16, ei, ea, agg);
    gru_mfma_kernel<<<ggrid, 256, 0, stream>>>(agg, hA, hB, wih16, whh16, b_ih, b_hh);

    // layer 1: hB -> m16 -> agg -> hA
    mgemm_kernel<<<ggrid, 256, 0, stream>>>(hB, ggT + FHC * FHC, m16);
    hipMemsetAsync(agg, 0, nodeE * sizeof(float), stream);
    scatter_kernel<<<N_EDGES / 4, 256, 0, stream>>>(m16, ei, ea, agg);
    gru_mfma_kernel<<<ggrid, 256, 0, stream>>>(agg, hB, hA, wih16, whh16, b_ih, b_hh);

    cnn_kernel<<<N_NODES / 4, 256, 0, stream>>>(hA, cnn_w, cnn_b, y1);
    head_kernel<<<NGRAPH, 256, 0, stream>>>(y1, l1w, l1b, l2w, l2b, out);
}

// Round 3
// 493.632 us; speedup vs baseline: 23.1507x; 7.8418x over previous
//
#include <hip/hip_runtime.h>
#include <math.h>

#define N_NODES 65536
#define N_EDGES 524288
#define IN_CH 128
#define FHC 256
#define NCLS 3
#define NPG 32
#define NGRAPH (N_NODES / NPG)

#define LDW 40  // shorts per LDS tile row (32 data + 8 pad) = 80B stride -> bank-uniform b128 reads

typedef __attribute__((ext_vector_type(8))) short bfrag;   // 8 bf16 = 4 VGPR (MFMA A/B)
typedef __attribute__((ext_vector_type(4))) float facc;    // 4 f32 (MFMA C/D)

__device__ inline float sigmoidf_(float x) { return 1.0f / (1.0f + expf(-x)); }

__device__ inline short f2bf(float f) {  // RNE float->bf16 bits
    union { float f; unsigned u; } v; v.f = f;
    unsigned r = v.u + 0x7fffu + ((v.u >> 16) & 1u);
    return (short)(r >> 16);
}
__device__ inline float bf2f(short s) {
    union { unsigned u; float f; } v; v.u = ((unsigned)(unsigned short)s) << 16;
    return v.f;
}

// ---------------- weight convert: gg_w -> transposed bf16, w_ih/w_hh -> bf16 ----------------
__global__ void convert_kernel(const float* __restrict__ gg_w, const float* __restrict__ wih,
                               const float* __restrict__ whh, short* __restrict__ ggT,
                               short* __restrict__ wih16, short* __restrict__ whh16) {
    int t = blockIdx.x * 256 + threadIdx.x;  // 0 .. 8*FHC*FHC-1
    if (t < 2 * FHC * FHC) {
        int i = t >> 16, r = t & 65535, n = r >> 8, k = r & 255;
        ggT[t] = f2bf(gg_w[i * FHC * FHC + k * FHC + n]);  // out [i][n][k]
    } else if (t < 2 * FHC * FHC + 3 * FHC * FHC) {
        int u = t - 2 * FHC * FHC;
        wih16[u] = f2bf(wih[u]);
    } else {
        int u = t - 5 * FHC * FHC;
        whh16[u] = f2bf(whh[u]);
    }
}

// ---------------- pad x [N,128] fp32 -> h [N,256] bf16 ----------------
__global__ void pad16_kernel(const float* __restrict__ x, short* __restrict__ h) {
    int idx = blockIdx.x * 256 + threadIdx.x;  // short4 granularity over N*64
    int c4 = idx & 63, n = idx >> 6;
    short4 v = {0, 0, 0, 0};
    if (c4 < 32) {
        float4 xv = reinterpret_cast<const float4*>(x)[n * 32 + c4];
        v.x = f2bf(xv.x); v.y = f2bf(xv.y); v.z = f2bf(xv.z); v.w = f2bf(xv.w);
    }
    reinterpret_cast<short4*>(h)[idx] = v;
}

// ================= CSR build =================
__global__ void hist_kernel(const int* __restrict__ ei, int* __restrict__ deg) {
    int e = blockIdx.x * 256 + threadIdx.x;
    atomicAdd(&deg[ei[N_EDGES + e]], 1);
}

__global__ void scan_reduce_kernel(const int* __restrict__ deg, int* __restrict__ bsum) {
    __shared__ int s[256];
    int t = threadIdx.x;
    s[t] = deg[blockIdx.x * 256 + t];
    __syncthreads();
    for (int off = 128; off > 0; off >>= 1) {
        if (t < off) s[t] += s[t + off];
        __syncthreads();
    }
    if (t == 0) bsum[blockIdx.x] = s[0];
}

__global__ void scan_bsum_kernel(const int* __restrict__ bsum, int* __restrict__ boff) {
    __shared__ int s[256];
    int t = threadIdx.x;
    int v = bsum[t];
    s[t] = v;
    __syncthreads();
    for (int off = 1; off < 256; off <<= 1) {
        int u = (t >= off) ? s[t - off] : 0;
        __syncthreads();
        s[t] += u;
        __syncthreads();
    }
    boff[t] = s[t] - v;  // exclusive
}

__global__ void scan_write_kernel(const int* __restrict__ deg, const int* __restrict__ boff,
                                  int* __restrict__ rowptr, int* __restrict__ cur) {
    __shared__ int s[256];
    int t = threadIdx.x, gid = blockIdx.x * 256 + t;
    int v = deg[gid];
    s[t] = v;
    __syncthreads();
    for (int off = 1; off < 256; off <<= 1) {
        int u = (t >= off) ? s[t - off] : 0;
        __syncthreads();
        s[t] += u;
        __syncthreads();
    }
    int excl = boff[blockIdx.x] + s[t] - v;
    rowptr[gid] = excl;
    cur[gid] = excl;
    if (gid == N_NODES - 1) rowptr[N_NODES] = excl + v;
}

__global__ void fill_kernel(const int* __restrict__ ei, const float* __restrict__ ea,
                            int* __restrict__ cur, int2* __restrict__ csr) {
    int e = blockIdx.x * 256 + threadIdx.x;
    int dst = ei[N_EDGES + e];
    int pos = atomicAdd(&cur[dst], 1);
    csr[pos] = make_int2(ei[e], __float_as_int(ea[e]));
}

// ---------------- gather: agg16[n] = sum_{e: dst=n} m16[src_e] * w_e ----------------
__global__ __launch_bounds__(256) void gather_kernel(const short* __restrict__ m,
                                                     const int* __restrict__ rowptr,
                                                     const int2* __restrict__ csr,
                                                     short* __restrict__ agg16) {
    int node = blockIdx.x * 4 + (threadIdx.x >> 6);
    int lane = threadIdx.x & 63;
    int beg = rowptr[node], end = rowptr[node + 1];
    float a0 = 0.f, a1 = 0.f, a2 = 0.f, a3 = 0.f;
    for (int j = beg; j < end; ++j) {
        int2 e = csr[j];
        float w = __int_as_float(e.y);
        short4 v = reinterpret_cast<const short4*>(m)[(size_t)e.x * 64 + lane];
        a0 += bf2f(v.x) * w;
        a1 += bf2f(v.y) * w;
        a2 += bf2f(v.z) * w;
        a3 += bf2f(v.w) * w;
    }
    short4 o;
    o.x = f2bf(a0); o.y = f2bf(a1); o.z = f2bf(a2); o.w = f2bf(a3);
    reinterpret_cast<short4*>(agg16)[(size_t)node * 64 + lane] = o;
}

// ---------------- m16[M,256] = h16[M,256] @ W[256(n),256(k)]^T  (bf16 MFMA) ----------------
__global__ __launch_bounds__(256) void mgemm_kernel(const short* __restrict__ A,
                                                    const short* __restrict__ W,
                                                    short* __restrict__ C) {
    __shared__ __align__(16) short As[64 * LDW];
    __shared__ __align__(16) short Ws[64 * LDW];
    int tid = threadIdx.x;
    int m0 = blockIdx.x * 64, n0 = blockIdx.y * 64;
    int srow = tid >> 2, sch = tid & 3;
    int lane = tid & 63, wv = tid >> 6, fr = lane & 15, fc = lane >> 4;
    facc acc[4] = {};
    for (int k0 = 0; k0 < FHC; k0 += 32) {
        *reinterpret_cast<int4*>(&As[srow * LDW + sch * 8]) =
            *reinterpret_cast<const int4*>(&A[(size_t)(m0 + srow) * FHC + k0 + sch * 8]);
        *reinterpret_cast<int4*>(&Ws[srow * LDW + sch * 8]) =
            *reinterpret_cast<const int4*>(&W[(size_t)(n0 + srow) * FHC + k0 + sch * 8]);
        __syncthreads();
        bfrag af = *reinterpret_cast<bfrag*>(&As[(wv * 16 + fr) * LDW + fc * 8]);
#pragma unroll
        for (int cf = 0; cf < 4; ++cf) {
            bfrag bf_ = *reinterpret_cast<bfrag*>(&Ws[(cf * 16 + fr) * LDW + fc * 8]);
            acc[cf] = __builtin_amdgcn_mfma_f32_16x16x32_bf16(af, bf_, acc[cf], 0, 0, 0);
        }
        __syncthreads();
    }
#pragma unroll
    for (int cf = 0; cf < 4; ++cf)
#pragma unroll
        for (int r = 0; r < 4; ++r) {
            int node = m0 + wv * 16 + fc * 4 + r;
            int c = n0 + cf * 16 + fr;
            C[(size_t)node * FHC + c] = f2bf(acc[cf][r]);
        }
}

// ---------------- fused GRU via MFMA: hout = GRU(agg16, hin) ----------------
__global__ __launch_bounds__(256) void gru_mfma_kernel(
    const short* __restrict__ agg16, const short* __restrict__ hin, short* __restrict__ hout,
    const short* __restrict__ wih16, const short* __restrict__ whh16,
    const float* __restrict__ bih, const float* __restrict__ bhh) {
    __shared__ __align__(16) short AggS[64 * LDW], HS[64 * LDW];
    __shared__ __align__(16) short WirS[64 * LDW], WizS[64 * LDW], WigS[64 * LDW];
    __shared__ __align__(16) short WhrS[64 * LDW], WhzS[64 * LDW], WhgS[64 * LDW];
    int tid = threadIdx.x;
    int m0 = blockIdx.x * 64, c0 = blockIdx.y * 64;
    int srow = tid >> 2, sch = tid & 3;
    int lane = tid & 63, wv = tid >> 6, fr = lane & 15, fc = lane >> 4;
    facc aR[4] = {}, aZ[4] = {}, aG[4] = {}, aH[4] = {};
    for (int k0 = 0; k0 < FHC; k0 += 32) {
        size_t koff = (size_t)k0 + sch * 8;
        *reinterpret_cast<int4*>(&AggS[srow * LDW + sch * 8]) =
            *reinterpret_cast<const int4*>(&agg16[(size_t)(m0 + srow) * FHC + koff]);
        *reinterpret_cast<int4*>(&HS[srow * LDW + sch * 8]) =
            *reinterpret_cast<const int4*>(&hin[(size_t)(m0 + srow) * FHC + koff]);
        *reinterpret_cast<int4*>(&WirS[srow * LDW + sch * 8]) =
            *reinterpret_cast<const int4*>(&wih16[(size_t)(c0 + srow) * FHC + koff]);
        *reinterpret_cast<int4*>(&WizS[srow * LDW + sch * 8]) =
            *reinterpret_cast<const int4*>(&wih16[(size_t)(c0 + 256 + srow) * FHC + koff]);
        *reinterpret_cast<int4*>(&WigS[srow * LDW + sch * 8]) =
            *reinterpret_cast<const int4*>(&wih16[(size_t)(c0 + 512 + srow) * FHC + koff]);
        *reinterpret_cast<int4*>(&WhrS[srow * LDW + sch * 8]) =
            *reinterpret_cast<const int4*>(&whh16[(size_t)(c0 + srow) * FHC + koff]);
        *reinterpret_cast<int4*>(&WhzS[srow * LDW + sch * 8]) =
            *reinterpret_cast<const int4*>(&whh16[(size_t)(c0 + 256 + srow) * FHC + koff]);
        *reinterpret_cast<int4*>(&WhgS[srow * LDW + sch * 8]) =
            *reinterpret_cast<const int4*>(&whh16[(size_t)(c0 + 512 + srow) * FHC + koff]);
        __syncthreads();
        bfrag aggF = *reinterpret_cast<bfrag*>(&AggS[(wv * 16 + fr) * LDW + fc * 8]);
        bfrag hF = *reinterpret_cast<bfrag*>(&HS[(wv * 16 + fr) * LDW + fc * 8]);
#pragma unroll
        for (int cf = 0; cf < 4; ++cf) {
            int ro = (cf * 16 + fr) * LDW + fc * 8;
            bfrag wir = *reinterpret_cast<bfrag*>(&WirS[ro]);
            bfrag wiz = *reinterpret_cast<bfrag*>(&WizS[ro]);
            bfrag wig = *reinterpret_cast<bfrag*>(&WigS[ro]);
            bfrag whr = *reinterpret_cast<bfrag*>(&WhrS[ro]);
            bfrag whz = *reinterpret_cast<bfrag*>(&WhzS[ro]);
            bfrag whg = *reinterpret_cast<bfrag*>(&WhgS[ro]);
            aR[cf] = __builtin_amdgcn_mfma_f32_16x16x32_bf16(aggF, wir, aR[cf], 0, 0, 0);
            aR[cf] = __builtin_amdgcn_mfma_f32_16x16x32_bf16(hF, whr, aR[cf], 0, 0, 0);
            aZ[cf] = __builtin_amdgcn_mfma_f32_16x16x32_bf16(aggF, wiz, aZ[cf], 0, 0, 0);
            aZ[cf] = __builtin_amdgcn_mfma_f32_16x16x32_bf16(hF, whz, aZ[cf], 0, 0, 0);
            aG[cf] = __builtin_amdgcn_mfma_f32_16x16x32_bf16(aggF, wig, aG[cf], 0, 0, 0);
            aH[cf] = __builtin_amdgcn_mfma_f32_16x16x32_bf16(hF, whg, aH[cf], 0, 0, 0);
        }
        __syncthreads();
    }
#pragma unroll
    for (int cf = 0; cf < 4; ++cf) {
        int c = c0 + cf * 16 + fr;
        float br = bih[c] + bhh[c];
        float bz = bih[c + 256] + bhh[c + 256];
        float big = bih[c + 512];
        float bhg = bhh[c + 512];
#pragma unroll
        for (int r = 0; r < 4; ++r) {
            int node = m0 + wv * 16 + fc * 4 + r;
            float hold = bf2f(hin[(size_t)node * FHC + c]);
            float rg = sigmoidf_(aR[cf][r] + br);
            float z = sigmoidf_(aZ[cf][r] + bz);
            float g = tanhf(aG[cf][r] + big + rg * (aH[cf][r] + bhg));
            hout[(size_t)node * FHC + c] = f2bf((1.f - z) * g + z * hold);
        }
    }
}

// ---------------- conv1d(k=1) head: y1[n] = relu(sum_f relu(h[n,f])*w[f] + b) ----------------
__global__ void cnn_kernel(const short* __restrict__ h, const float* __restrict__ w,
                           const float* __restrict__ b, float* __restrict__ y1) {
    int node = blockIdx.x * 4 + (threadIdx.x >> 6);
    int lane = threadIdx.x & 63;
    short4 hv = reinterpret_cast<const short4*>(h)[(size_t)node * 64 + lane];
    float4 wv = reinterpret_cast<const float4*>(w)[lane];
    float p = fmaxf(bf2f(hv.x), 0.f) * wv.x + fmaxf(bf2f(hv.y), 0.f) * wv.y +
              fmaxf(bf2f(hv.z), 0.f) * wv.z + fmaxf(bf2f(hv.w), 0.f) * wv.w;
#pragma unroll
    for (int off = 32; off > 0; off >>= 1) p += __shfl_down(p, off, 64);
    if (lane == 0) y1[node] = fmaxf(p + b[0], 0.f);
}

// ---------------- per-graph MLP + softmax ----------------
__global__ __launch_bounds__(256) void head_kernel(
    const float* __restrict__ y1, const float* __restrict__ l1w,
    const float* __restrict__ l1b, const float* __restrict__ l2w,
    const float* __restrict__ l2b, float* __restrict__ out) {
    __shared__ float ys[32];
    __shared__ float zs[256];
    __shared__ float os[3];
    int b = blockIdx.x, tid = threadIdx.x;
    if (tid < 32) ys[tid] = y1[b * 32 + tid];
    __syncthreads();
    float acc = l1b[tid];
#pragma unroll
    for (int k = 0; k < 32; ++k) acc += ys[k] * l1w[tid * 32 + k];
    zs[tid] = fmaxf(acc, 0.f);
    __syncthreads();
    int wave = tid >> 6, lane = tid & 63;
    if (wave < 3) {
        float p = 0.f;
#pragma unroll
        for (int j = 0; j < 4; ++j) p += zs[lane + j * 64] * l2w[wave * 256 + lane + j * 64];
#pragma unroll
        for (int off = 32; off > 0; off >>= 1) p += __shfl_down(p, off, 64);
        if (lane == 0) os[wave] = p + l2b[wave];
    }
    __syncthreads();
    if (tid == 0) {
        float mx = fmaxf(os[0], fmaxf(os[1], os[2]));
        float e0 = expf(os[0] - mx), e1 = expf(os[1] - mx), e2 = expf(os[2] - mx);
        float s = e0 + e1 + e2;
        out[b * 3 + 0] = e0 / s;
        out[b * 3 + 1] = e1 / s;
        out[b * 3 + 2] = e2 / s;
    }
}

extern "C" void kernel_launch(void* const* d_in, const int* in_sizes, int n_in,
                              void* d_out, int out_size, void* d_ws, size_t ws_size,
                              hipStream_t stream) {
    const float* x = (const float*)d_in[0];
    const int* ei = (const int*)d_in[1];
    const float* ea = (const float*)d_in[2];
    const float* gg_w = (const float*)d_in[3];
    const float* w_ih = (const float*)d_in[4];
    const float* w_hh = (const float*)d_in[5];
    const float* b_ih = (const float*)d_in[6];
    const float* b_hh = (const float*)d_in[7];
    const float* cnn_w = (const float*)d_in[8];
    const float* cnn_b = (const float*)d_in[9];
    const float* l1w = (const float*)d_in[10];
    const float* l1b = (const float*)d_in[11];
    const float* l2w = (const float*)d_in[12];
    const float* l2b = (const float*)d_in[13];
    float* out = (float*)d_out;

    const size_t nodeE = (size_t)N_NODES * FHC;
    char* p = (char*)d_ws;
    short* hA = (short*)p;      p += nodeE * 2;
    short* hB = (short*)p;      p += nodeE * 2;
    short* m16 = (short*)p;     p += nodeE * 2;
    short* agg16 = (short*)p;   p += nodeE * 2;
    short* ggT = (short*)p;     p += (size_t)2 * FHC * FHC * 2;
    short* wih16 = (short*)p;   p += (size_t)3 * FHC * FHC * 2;
    short* whh16 = (short*)p;   p += (size_t)3 * FHC * FHC * 2;
    float* y1 = (float*)p;      p += (size_t)N_NODES * 4;
    int* deg = (int*)p;         p += (size_t)N_NODES * 4;
    int* rowptr = (int*)p;      p += (size_t)(N_NODES + 4) * 4;
    int* cur = (int*)p;         p += (size_t)N_NODES * 4;
    int* bsum = (int*)p;        p += 256 * 4;
    int* boff = (int*)p;        p += 256 * 4;
    int2* csr = (int2*)p;       p += (size_t)N_EDGES * 8;

    dim3 ggrid(N_NODES / 64, FHC / 64);

    // weights + input prep
    convert_kernel<<<8 * FHC * FHC / 256, 256, 0, stream>>>(gg_w, w_ih, w_hh, ggT, wih16, whh16);
    pad16_kernel<<<N_NODES * 64 / 256, 256, 0, stream>>>(x, hA);

    // CSR build (per call; graph is a fixed input)
    hipMemsetAsync(deg, 0, (size_t)N_NODES * 4, stream);
    hist_kernel<<<N_EDGES / 256, 256, 0, stream>>>(ei, deg);
    scan_reduce_kernel<<<N_NODES / 256, 256, 0, stream>>>(deg, bsum);
    scan_bsum_kernel<<<1, 256, 0, stream>>>(bsum, boff);
    scan_write_kernel<<<N_NODES / 256, 256, 0, stream>>>(deg, boff, rowptr, cur);
    fill_kernel<<<N_EDGES / 256, 256, 0, stream>>>(ei, ea, cur, csr);

    // layer 0: hA -> m16 -> agg16 -> hB
    mgemm_kernel<<<ggrid, 256, 0, stream>>>(hA, ggT, m16);
    gather_kernel<<<N_NODES / 4, 256, 0, stream>>>(m16, rowptr, csr, agg16);
    gru_mfma_kernel<<<ggrid, 256, 0, stream>>>(agg16, hA, hB, wih16, whh16, b_ih, b_hh);

    // layer 1: hB -> m16 -> agg16 -> hA
    mgemm_kernel<<<ggrid, 256, 0, stream>>>(hB, ggT + FHC * FHC, m16);
    gather_kernel<<<N_NODES / 4, 256, 0, stream>>>(m16, rowptr, csr, agg16);
    gru_mfma_kernel<<<ggrid, 256, 0, stream>>>(agg16, hB, hA, wih16, whh16, b_ih, b_hh);

    cnn_kernel<<<N_NODES / 4, 256, 0, stream>>>(hA, cnn_w, cnn_b, y1);
    head_kernel<<<NGRAPH, 256, 0, stream>>>(y1, l1w, l1b, l2w, l2b, out);
}

// Round 4
// 470.669 us; speedup vs baseline: 24.2801x; 1.0488x over previous
//
#include <hip/hip_runtime.h>
#include <math.h>

#define N_NODES 65536
#define N_EDGES 524288
#define IN_CH 128
#define FHC 256
#define NCLS 3
#define NPG 32
#define NGRAPH (N_NODES / NPG)

#define BLKM 128  // rows per block (4 waves x 32 rows)
#define LDW 40    // shorts per LDS row (32 data + 8 pad) = 80B stride

typedef __attribute__((ext_vector_type(8))) short bfrag;   // 8 bf16 = 4 VGPR (MFMA A/B)
typedef __attribute__((ext_vector_type(4))) float facc;    // 4 f32 (MFMA C/D)

__device__ inline float sigmoidf_(float x) { return 1.0f / (1.0f + expf(-x)); }

__device__ inline short f2bf(float f) {  // RNE float->bf16 bits
    union { float f; unsigned u; } v; v.f = f;
    unsigned r = v.u + 0x7fffu + ((v.u >> 16) & 1u);
    return (short)(r >> 16);
}
__device__ inline float bf2f(short s) {
    union { unsigned u; float f; } v; v.u = ((unsigned)(unsigned short)s) << 16;
    return v.f;
}

// ---------------- weight convert: gg_w -> transposed bf16, w_ih/w_hh -> bf16 ----------------
__global__ void convert_kernel(const float* __restrict__ gg_w, const float* __restrict__ wih,
                               const float* __restrict__ whh, short* __restrict__ ggT,
                               short* __restrict__ wih16, short* __restrict__ whh16) {
    int t = blockIdx.x * 256 + threadIdx.x;  // 0 .. 8*FHC*FHC-1
    if (t < 2 * FHC * FHC) {
        int i = t >> 16, r = t & 65535, n = r >> 8, k = r & 255;
        ggT[t] = f2bf(gg_w[i * FHC * FHC + k * FHC + n]);  // out [i][n][k]
    } else if (t < 2 * FHC * FHC + 3 * FHC * FHC) {
        int u = t - 2 * FHC * FHC;
        wih16[u] = f2bf(wih[u]);
    } else {
        int u = t - 5 * FHC * FHC;
        whh16[u] = f2bf(whh[u]);
    }
}

// ---------------- pad x [N,128] fp32 -> h [N,256] bf16 ----------------
__global__ void pad16_kernel(const float* __restrict__ x, short* __restrict__ h) {
    int idx = blockIdx.x * 256 + threadIdx.x;  // short4 granularity over N*64
    int c4 = idx & 63, n = idx >> 6;
    short4 v = {0, 0, 0, 0};
    if (c4 < 32) {
        float4 xv = reinterpret_cast<const float4*>(x)[n * 32 + c4];
        v.x = f2bf(xv.x); v.y = f2bf(xv.y); v.z = f2bf(xv.z); v.w = f2bf(xv.w);
    }
    reinterpret_cast<short4*>(h)[idx] = v;
}

// ================= CSR build =================
__global__ void hist_kernel(const int* __restrict__ ei, int* __restrict__ deg) {
    int e = blockIdx.x * 256 + threadIdx.x;
    atomicAdd(&deg[ei[N_EDGES + e]], 1);
}

__global__ void scan_reduce_kernel(const int* __restrict__ deg, int* __restrict__ bsum) {
    __shared__ int s[256];
    int t = threadIdx.x;
    s[t] = deg[blockIdx.x * 256 + t];
    __syncthreads();
    for (int off = 128; off > 0; off >>= 1) {
        if (t < off) s[t] += s[t + off];
        __syncthreads();
    }
    if (t == 0) bsum[blockIdx.x] = s[0];
}

__global__ void scan_bsum_kernel(const int* __restrict__ bsum, int* __restrict__ boff) {
    __shared__ int s[256];
    int t = threadIdx.x;
    int v = bsum[t];
    s[t] = v;
    __syncthreads();
    for (int off = 1; off < 256; off <<= 1) {
        int u = (t >= off) ? s[t - off] : 0;
        __syncthreads();
        s[t] += u;
        __syncthreads();
    }
    boff[t] = s[t] - v;  // exclusive
}

__global__ void scan_write_kernel(const int* __restrict__ deg, const int* __restrict__ boff,
                                  int* __restrict__ rowptr, int* __restrict__ cur) {
    __shared__ int s[256];
    int t = threadIdx.x, gid = blockIdx.x * 256 + t;
    int v = deg[gid];
    s[t] = v;
    __syncthreads();
    for (int off = 1; off < 256; off <<= 1) {
        int u = (t >= off) ? s[t - off] : 0;
        __syncthreads();
        s[t] += u;
        __syncthreads();
    }
    int excl = boff[blockIdx.x] + s[t] - v;
    rowptr[gid] = excl;
    cur[gid] = excl;
    if (gid == N_NODES - 1) rowptr[N_NODES] = excl + v;
}

__global__ void fill_kernel(const int* __restrict__ ei, const float* __restrict__ ea,
                            int* __restrict__ cur, int2* __restrict__ csr) {
    int e = blockIdx.x * 256 + threadIdx.x;
    int dst = ei[N_EDGES + e];
    int pos = atomicAdd(&cur[dst], 1);
    csr[pos] = make_int2(ei[e], __float_as_int(ea[e]));
}

// ---------------- gather: agg16[n] = sum_{e: dst=n} m16[src_e] * w_e ----------------
__global__ __launch_bounds__(256) void gather_kernel(const short* __restrict__ m,
                                                     const int* __restrict__ rowptr,
                                                     const int2* __restrict__ csr,
                                                     short* __restrict__ agg16) {
    int node = blockIdx.x * 4 + (threadIdx.x >> 6);
    int lane = threadIdx.x & 63;
    int beg = rowptr[node], end = rowptr[node + 1];
    float a0 = 0.f, a1 = 0.f, a2 = 0.f, a3 = 0.f;
    for (int j = beg; j < end; ++j) {
        int2 e = csr[j];
        float w = __int_as_float(e.y);
        short4 v = reinterpret_cast<const short4*>(m)[(size_t)e.x * 64 + lane];
        a0 += bf2f(v.x) * w;
        a1 += bf2f(v.y) * w;
        a2 += bf2f(v.z) * w;
        a3 += bf2f(v.w) * w;
    }
    short4 o;
    o.x = f2bf(a0); o.y = f2bf(a1); o.z = f2bf(a2); o.w = f2bf(a3);
    reinterpret_cast<short4*>(agg16)[(size_t)node * 64 + lane] = o;
}

// ---------------- m16[M,256] = h16[M,256] @ W[256(n),256(k)]^T  (bf16 MFMA) ----------------
// 4 waves x 32 rows = 128-row block, 64 cols
__global__ __launch_bounds__(256, 2) void mgemm_kernel(const short* __restrict__ A,
                                                       const short* __restrict__ W,
                                                       short* __restrict__ C) {
    __shared__ __align__(16) short As[BLKM * LDW];
    __shared__ __align__(16) short Ws[64 * LDW];
    int tid = threadIdx.x;
    int m0 = blockIdx.x * BLKM, n0 = blockIdx.y * 64;
    int arow = tid >> 2, aslot = tid & 3;
    int lane = tid & 63, wv = tid >> 6, fr = lane & 15, fc = lane >> 4;
    facc acc[2][4] = {};
    for (int k0 = 0; k0 < FHC; k0 += 32) {
        int koff = k0 + aslot * 8;
        *reinterpret_cast<int4*>(&As[arow * LDW + aslot * 8]) =
            *reinterpret_cast<const int4*>(&A[(size_t)(m0 + arow) * FHC + koff]);
        *reinterpret_cast<int4*>(&As[(arow + 64) * LDW + aslot * 8]) =
            *reinterpret_cast<const int4*>(&A[(size_t)(m0 + 64 + arow) * FHC + koff]);
        *reinterpret_cast<int4*>(&Ws[arow * LDW + aslot * 8]) =
            *reinterpret_cast<const int4*>(&W[(size_t)(n0 + arow) * FHC + koff]);
        __syncthreads();
        bfrag a0 = *reinterpret_cast<bfrag*>(&As[(wv * 32 + fr) * LDW + fc * 8]);
        bfrag a1 = *reinterpret_cast<bfrag*>(&As[(wv * 32 + 16 + fr) * LDW + fc * 8]);
#pragma unroll
        for (int cf = 0; cf < 4; ++cf) {
            bfrag b = *reinterpret_cast<bfrag*>(&Ws[(cf * 16 + fr) * LDW + fc * 8]);
            acc[0][cf] = __builtin_amdgcn_mfma_f32_16x16x32_bf16(a0, b, acc[0][cf], 0, 0, 0);
            acc[1][cf] = __builtin_amdgcn_mfma_f32_16x16x32_bf16(a1, b, acc[1][cf], 0, 0, 0);
        }
        __syncthreads();
    }
#pragma unroll
    for (int s = 0; s < 2; ++s)
#pragma unroll
        for (int cf = 0; cf < 4; ++cf)
#pragma unroll
            for (int r = 0; r < 4; ++r) {
                int node = m0 + wv * 32 + s * 16 + fc * 4 + r;
                int c = n0 + cf * 16 + fr;
                C[(size_t)node * FHC + c] = f2bf(acc[s][cf][r]);
            }
}

// ---------------- fused GRU via MFMA: hout = GRU(agg16, hin) ----------------
// 4 waves x 32 rows = 128-row block, 64 gate-cols; 48 MFMA per wave per k-step
__global__ __launch_bounds__(256, 2) void gru_mfma_kernel(
    const short* __restrict__ agg16, const short* __restrict__ hin, short* __restrict__ hout,
    const short* __restrict__ wih16, const short* __restrict__ whh16,
    const float* __restrict__ bih, const float* __restrict__ bhh) {
    __shared__ __align__(16) short AggS[BLKM * LDW], HS[BLKM * LDW];
    __shared__ __align__(16) short WS[6][64 * LDW];  // wir,wiz,wig,whr,whz,whg
    int tid = threadIdx.x;
    int m0 = blockIdx.x * BLKM, c0 = blockIdx.y * 64;
    int arow = tid >> 2, aslot = tid & 3;
    int lane = tid & 63, wv = tid >> 6, fr = lane & 15, fc = lane >> 4;
    facc aR[2][4] = {}, aZ[2][4] = {}, aG[2][4] = {}, aH[2][4] = {};
    for (int k0 = 0; k0 < FHC; k0 += 32) {
        int koff = k0 + aslot * 8;
        *reinterpret_cast<int4*>(&AggS[arow * LDW + aslot * 8]) =
            *reinterpret_cast<const int4*>(&agg16[(size_t)(m0 + arow) * FHC + koff]);
        *reinterpret_cast<int4*>(&AggS[(arow + 64) * LDW + aslot * 8]) =
            *reinterpret_cast<const int4*>(&agg16[(size_t)(m0 + 64 + arow) * FHC + koff]);
        *reinterpret_cast<int4*>(&HS[arow * LDW + aslot * 8]) =
            *reinterpret_cast<const int4*>(&hin[(size_t)(m0 + arow) * FHC + koff]);
        *reinterpret_cast<int4*>(&HS[(arow + 64) * LDW + aslot * 8]) =
            *reinterpret_cast<const int4*>(&hin[(size_t)(m0 + 64 + arow) * FHC + koff]);
        *reinterpret_cast<int4*>(&WS[0][arow * LDW + aslot * 8]) =
            *reinterpret_cast<const int4*>(&wih16[(size_t)(c0 + arow) * FHC + koff]);
        *reinterpret_cast<int4*>(&WS[1][arow * LDW + aslot * 8]) =
            *reinterpret_cast<const int4*>(&wih16[(size_t)(c0 + 256 + arow) * FHC + koff]);
        *reinterpret_cast<int4*>(&WS[2][arow * LDW + aslot * 8]) =
            *reinterpret_cast<const int4*>(&wih16[(size_t)(c0 + 512 + arow) * FHC + koff]);
        *reinterpret_cast<int4*>(&WS[3][arow * LDW + aslot * 8]) =
            *reinterpret_cast<const int4*>(&whh16[(size_t)(c0 + arow) * FHC + koff]);
        *reinterpret_cast<int4*>(&WS[4][arow * LDW + aslot * 8]) =
            *reinterpret_cast<const int4*>(&whh16[(size_t)(c0 + 256 + arow) * FHC + koff]);
        *reinterpret_cast<int4*>(&WS[5][arow * LDW + aslot * 8]) =
            *reinterpret_cast<const int4*>(&whh16[(size_t)(c0 + 512 + arow) * FHC + koff]);
        __syncthreads();
        bfrag ag0 = *reinterpret_cast<bfrag*>(&AggS[(wv * 32 + fr) * LDW + fc * 8]);
        bfrag ag1 = *reinterpret_cast<bfrag*>(&AggS[(wv * 32 + 16 + fr) * LDW + fc * 8]);
        bfrag h0 = *reinterpret_cast<bfrag*>(&HS[(wv * 32 + fr) * LDW + fc * 8]);
        bfrag h1 = *reinterpret_cast<bfrag*>(&HS[(wv * 32 + 16 + fr) * LDW + fc * 8]);
#pragma unroll
        for (int cf = 0; cf < 4; ++cf) {
            int ro = (cf * 16 + fr) * LDW + fc * 8;
            bfrag wir = *reinterpret_cast<bfrag*>(&WS[0][ro]);
            bfrag wiz = *reinterpret_cast<bfrag*>(&WS[1][ro]);
            bfrag wig = *reinterpret_cast<bfrag*>(&WS[2][ro]);
            bfrag whr = *reinterpret_cast<bfrag*>(&WS[3][ro]);
            bfrag whz = *reinterpret_cast<bfrag*>(&WS[4][ro]);
            bfrag whg = *reinterpret_cast<bfrag*>(&WS[5][ro]);
            aR[0][cf] = __builtin_amdgcn_mfma_f32_16x16x32_bf16(ag0, wir, aR[0][cf], 0, 0, 0);
            aR[1][cf] = __builtin_amdgcn_mfma_f32_16x16x32_bf16(ag1, wir, aR[1][cf], 0, 0, 0);
            aR[0][cf] = __builtin_amdgcn_mfma_f32_16x16x32_bf16(h0, whr, aR[0][cf], 0, 0, 0);
            aR[1][cf] = __builtin_amdgcn_mfma_f32_16x16x32_bf16(h1, whr, aR[1][cf], 0, 0, 0);
            aZ[0][cf] = __builtin_amdgcn_mfma_f32_16x16x32_bf16(ag0, wiz, aZ[0][cf], 0, 0, 0);
            aZ[1][cf] = __builtin_amdgcn_mfma_f32_16x16x32_bf16(ag1, wiz, aZ[1][cf], 0, 0, 0);
            aZ[0][cf] = __builtin_amdgcn_mfma_f32_16x16x32_bf16(h0, whz, aZ[0][cf], 0, 0, 0);
            aZ[1][cf] = __builtin_amdgcn_mfma_f32_16x16x32_bf16(h1, whz, aZ[1][cf], 0, 0, 0);
            aG[0][cf] = __builtin_amdgcn_mfma_f32_16x16x32_bf16(ag0, wig, aG[0][cf], 0, 0, 0);
            aG[1][cf] = __builtin_amdgcn_mfma_f32_16x16x32_bf16(ag1, wig, aG[1][cf], 0, 0, 0);
            aH[0][cf] = __builtin_amdgcn_mfma_f32_16x16x32_bf16(h0, whg, aH[0][cf], 0, 0, 0);
            aH[1][cf] = __builtin_amdgcn_mfma_f32_16x16x32_bf16(h1, whg, aH[1][cf], 0, 0, 0);
        }
        __syncthreads();
    }
#pragma unroll
    for (int cf = 0; cf < 4; ++cf) {
        int c = c0 + cf * 16 + fr;
        float br = bih[c] + bhh[c];
        float bz = bih[c + 256] + bhh[c + 256];
        float big = bih[c + 512];
        float bhg = bhh[c + 512];
#pragma unroll
        for (int s = 0; s < 2; ++s)
#pragma unroll
            for (int r = 0; r < 4; ++r) {
                int node = m0 + wv * 32 + s * 16 + fc * 4 + r;
                float hold = bf2f(hin[(size_t)node * FHC + c]);
                float rg = sigmoidf_(aR[s][cf][r] + br);
                float z = sigmoidf_(aZ[s][cf][r] + bz);
                float g = tanhf(aG[s][cf][r] + big + rg * (aH[s][cf][r] + bhg));
                hout[(size_t)node * FHC + c] = f2bf((1.f - z) * g + z * hold);
            }
    }
}

// ---------------- conv1d(k=1) head: y1[n] = relu(sum_f relu(h[n,f])*w[f] + b) ----------------
__global__ void cnn_kernel(const short* __restrict__ h, const float* __restrict__ w,
                           const float* __restrict__ b, float* __restrict__ y1) {
    int node = blockIdx.x * 4 + (threadIdx.x >> 6);
    int lane = threadIdx.x & 63;
    short4 hv = reinterpret_cast<const short4*>(h)[(size_t)node * 64 + lane];
    float4 wv = reinterpret_cast<const float4*>(w)[lane];
    float p = fmaxf(bf2f(hv.x), 0.f) * wv.x + fmaxf(bf2f(hv.y), 0.f) * wv.y +
              fmaxf(bf2f(hv.z), 0.f) * wv.z + fmaxf(bf2f(hv.w), 0.f) * wv.w;
#pragma unroll
    for (int off = 32; off > 0; off >>= 1) p += __shfl_down(p, off, 64);
    if (lane == 0) y1[node] = fmaxf(p + b[0], 0.f);
}

// ---------------- per-graph MLP + softmax ----------------
__global__ __launch_bounds__(256) void head_kernel(
    const float* __restrict__ y1, const float* __restrict__ l1w,
    const float* __restrict__ l1b, const float* __restrict__ l2w,
    const float* __restrict__ l2b, float* __restrict__ out) {
    __shared__ float ys[32];
    __shared__ float zs[256];
    __shared__ float os[3];
    int b = blockIdx.x, tid = threadIdx.x;
    if (tid < 32) ys[tid] = y1[b * 32 + tid];
    __syncthreads();
    float acc = l1b[tid];
#pragma unroll
    for (int k = 0; k < 32; ++k) acc += ys[k] * l1w[tid * 32 + k];
    zs[tid] = fmaxf(acc, 0.f);
    __syncthreads();
    int wave = tid >> 6, lane = tid & 63;
    if (wave < 3) {
        float p = 0.f;
#pragma unroll
        for (int j = 0; j < 4; ++j) p += zs[lane + j * 64] * l2w[wave * 256 + lane + j * 64];
#pragma unroll
        for (int off = 32; off > 0; off >>= 1) p += __shfl_down(p, off, 64);
        if (lane == 0) os[wave] = p + l2b[wave];
    }
    __syncthreads();
    if (tid == 0) {
        float mx = fmaxf(os[0], fmaxf(os[1], os[2]));
        float e0 = expf(os[0] - mx), e1 = expf(os[1] - mx), e2 = expf(os[2] - mx);
        float s = e0 + e1 + e2;
        out[b * 3 + 0] = e0 / s;
        out[b * 3 + 1] = e1 / s;
        out[b * 3 + 2] = e2 / s;
    }
}

extern "C" void kernel_launch(void* const* d_in, const int* in_sizes, int n_in,
                              void* d_out, int out_size, void* d_ws, size_t ws_size,
                              hipStream_t stream) {
    const float* x = (const float*)d_in[0];
    const int* ei = (const int*)d_in[1];
    const float* ea = (const float*)d_in[2];
    const float* gg_w = (const float*)d_in[3];
    const float* w_ih = (const float*)d_in[4];
    const float* w_hh = (const float*)d_in[5];
    const float* b_ih = (const float*)d_in[6];
    const float* b_hh = (const float*)d_in[7];
    const float* cnn_w = (const float*)d_in[8];
    const float* cnn_b = (const float*)d_in[9];
    const float* l1w = (const float*)d_in[10];
    const float* l1b = (const float*)d_in[11];
    const float* l2w = (const float*)d_in[12];
    const float* l2b = (const float*)d_in[13];
    float* out = (float*)d_out;

    const size_t nodeE = (size_t)N_NODES * FHC;
    char* p = (char*)d_ws;
    short* hA = (short*)p;      p += nodeE * 2;
    short* hB = (short*)p;      p += nodeE * 2;
    short* m16 = (short*)p;     p += nodeE * 2;
    short* agg16 = (short*)p;   p += nodeE * 2;
    short* ggT = (short*)p;     p += (size_t)2 * FHC * FHC * 2;
    short* wih16 = (short*)p;   p += (size_t)3 * FHC * FHC * 2;
    short* whh16 = (short*)p;   p += (size_t)3 * FHC * FHC * 2;
    float* y1 = (float*)p;      p += (size_t)N_NODES * 4;
    int* deg = (int*)p;         p += (size_t)N_NODES * 4;
    int* rowptr = (int*)p;      p += (size_t)(N_NODES + 4) * 4;
    int* cur = (int*)p;         p += (size_t)N_NODES * 4;
    int* bsum = (int*)p;        p += 256 * 4;
    int* boff = (int*)p;        p += 256 * 4;
    int2* csr = (int2*)p;       p += (size_t)N_EDGES * 8;

    dim3 ggrid(N_NODES / BLKM, FHC / 64);

    // weights + input prep
    convert_kernel<<<8 * FHC * FHC / 256, 256, 0, stream>>>(gg_w, w_ih, w_hh, ggT, wih16, whh16);
    pad16_kernel<<<N_NODES * 64 / 256, 256, 0, stream>>>(x, hA);

    // CSR build (per call; graph is a fixed input)
    hipMemsetAsync(deg, 0, (size_t)N_NODES * 4, stream);
    hist_kernel<<<N_EDGES / 256, 256, 0, stream>>>(ei, deg);
    scan_reduce_kernel<<<N_NODES / 256, 256, 0, stream>>>(deg, bsum);
    scan_bsum_kernel<<<1, 256, 0, stream>>>(bsum, boff);
    scan_write_kernel<<<N_NODES / 256, 256, 0, stream>>>(deg, boff, rowptr, cur);
    fill_kernel<<<N_EDGES / 256, 256, 0, stream>>>(ei, ea, cur, csr);

    // layer 0: hA -> m16 -> agg16 -> hB
    mgemm_kernel<<<ggrid, 256, 0, stream>>>(hA, ggT, m16);
    gather_kernel<<<N_NODES / 4, 256, 0, stream>>>(m16, rowptr, csr, agg16);
    gru_mfma_kernel<<<ggrid, 256, 0, stream>>>(agg16, hA, hB, wih16, whh16, b_ih, b_hh);

    // layer 1: hB -> m16 -> agg16 -> hA
    mgemm_kernel<<<ggrid, 256, 0, stream>>>(hB, ggT + FHC * FHC, m16);
    gather_kernel<<<N_NODES / 4, 256, 0, stream>>>(m16, rowptr, csr, agg16);
    gru_mfma_kernel<<<ggrid, 256, 0, stream>>>(agg16, hB, hA, wih16, whh16, b_ih, b_hh);

    cnn_kernel<<<N_NODES / 4, 256, 0, stream>>>(hA, cnn_w, cnn_b, y1);
    head_kernel<<<NGRAPH, 256, 0, stream>>>(y1, l1w, l1b, l2w, l2b, out);
}